// Round 1
// baseline (2140.281 us; speedup 1.0000x reference)
//
#include <hip/hip_runtime.h>

#define NN 50000
#define EE 1600000
#define INDIM 1280
#define HID 256
#define HEADS 4
#define DHD 64
#define NCLS 6
#define NEG 0.2f
#define LNEPS 1e-5f

// ---------------- CSR build ----------------
__global__ void init_cnt_kernel(int* __restrict__ cnt) {
    int n = blockIdx.x * 256 + threadIdx.x;
    if (n < NN) cnt[n] = 1;  // self loop
}

__global__ void count_edges_kernel(const int* __restrict__ dst, int* __restrict__ cnt) {
    int e = blockIdx.x * 256 + threadIdx.x;
    if (e < EE) atomicAdd(&cnt[dst[e]], 1);
}

// single-block exclusive scan over n counts -> rowptr[0..n]
__global__ __launch_bounds__(1024) void scan_excl_kernel(const int* __restrict__ cnt,
                                                         int* __restrict__ rowptr, int n) {
    __shared__ int buf[1024];
    __shared__ int carry;
    int tid = threadIdx.x;
    if (tid == 0) { carry = 0; rowptr[0] = 0; }
    __syncthreads();
    for (int base = 0; base < n; base += 1024) {
        int i = base + tid;
        int v = (i < n) ? cnt[i] : 0;
        buf[tid] = v;
        __syncthreads();
        for (int off = 1; off < 1024; off <<= 1) {
            int t = (tid >= off) ? buf[tid - off] : 0;
            __syncthreads();
            buf[tid] += t;
            __syncthreads();
        }
        if (i < n) rowptr[i + 1] = carry + buf[tid];
        __syncthreads();
        if (tid == 0) carry += buf[1023];
        __syncthreads();
    }
}

__global__ void copy_i32_kernel(const int* __restrict__ src, int* __restrict__ dst, int n) {
    int i = blockIdx.x * 256 + threadIdx.x;
    if (i < n) dst[i] = src[i];
}

__global__ void fill_self_kernel(int* __restrict__ cursor, int* __restrict__ csr) {
    int n = blockIdx.x * 256 + threadIdx.x;
    if (n < NN) {
        int pos = atomicAdd(&cursor[n], 1);
        csr[pos] = n;
    }
}

__global__ void scatter_edges_kernel(const int* __restrict__ src, const int* __restrict__ dst,
                                     int* __restrict__ cursor, int* __restrict__ csr) {
    int e = blockIdx.x * 256 + threadIdx.x;
    if (e < EE) {
        int d = dst[e];
        int pos = atomicAdd(&cursor[d], 1);
        csr[pos] = src[e];
    }
}

// ---------------- fp32 tiled GEMM: C = act(A[M,K] @ B[K,Nc] + bias) ----------------
// BM=64, BN=64, BK=16; 256 threads; 4x4 micro-tile. K % 16 == 0, Nc % 64 == 0.
template <int ACT>
__global__ __launch_bounds__(256) void gemm_kernel(const float* __restrict__ A,
                                                   const float* __restrict__ B,
                                                   const float* __restrict__ bias,
                                                   float* __restrict__ C,
                                                   int M, int K, int Nc) {
    __shared__ float As[16][64];
    __shared__ float Bs[16][64];
    int m0 = blockIdx.x * 64, n0 = blockIdx.y * 64;
    int tid = threadIdx.x;
    int tx = tid & 15, ty = tid >> 4;
    float acc[4][4] = {};
    for (int k0 = 0; k0 < K; k0 += 16) {
#pragma unroll
        for (int i = 0; i < 4; i++) {
            int e = tid + i * 256;
            int m = e >> 4, k = e & 15;
            int gm = m0 + m;
            As[k][m] = (gm < M) ? A[(size_t)gm * K + k0 + k] : 0.f;
        }
#pragma unroll
        for (int i = 0; i < 4; i++) {
            int e = tid + i * 256;
            int k = e >> 6, nn = e & 63;
            Bs[k][nn] = B[(size_t)(k0 + k) * Nc + n0 + nn];
        }
        __syncthreads();
#pragma unroll
        for (int k = 0; k < 16; k++) {
            float a[4], b[4];
#pragma unroll
            for (int i = 0; i < 4; i++) a[i] = As[k][ty * 4 + i];
#pragma unroll
            for (int j = 0; j < 4; j++) b[j] = Bs[k][tx * 4 + j];
#pragma unroll
            for (int i = 0; i < 4; i++)
#pragma unroll
                for (int j = 0; j < 4; j++) acc[i][j] += a[i] * b[j];
        }
        __syncthreads();
    }
#pragma unroll
    for (int i = 0; i < 4; i++) {
        int gm = m0 + ty * 4 + i;
        if (gm < M) {
#pragma unroll
            for (int j = 0; j < 4; j++) {
                int gn = n0 + tx * 4 + j;
                float v = acc[i][j] + (bias ? bias[gn] : 0.f);
                if (ACT) v = fmaxf(v, 0.f);
                C[(size_t)gm * Nc + gn] = v;
            }
        }
    }
}

// ---------------- per-node attention logits: al[n][h] = sum_d xh[n][h*64+d]*a[h][d] ----------------
__global__ __launch_bounds__(256) void proj_al_kernel(const float* __restrict__ xh,
                                                      const float* __restrict__ a_src,
                                                      const float* __restrict__ a_dst,
                                                      float* __restrict__ al_s,
                                                      float* __restrict__ al_d) {
    int n = blockIdx.x * 4 + (threadIdx.x >> 6);
    if (n >= NN) return;
    int lane = threadIdx.x & 63;
    const float4* row = (const float4*)(xh + (size_t)n * HID);
    float4 v = row[lane];
    float4 as4 = ((const float4*)a_src)[lane];
    float4 ad4 = ((const float4*)a_dst)[lane];
    float ps = v.x * as4.x + v.y * as4.y + v.z * as4.z + v.w * as4.w;
    float pd = v.x * ad4.x + v.y * ad4.y + v.z * ad4.z + v.w * ad4.w;
#pragma unroll
    for (int off = 8; off > 0; off >>= 1) {
        ps += __shfl_down(ps, off, 16);
        pd += __shfl_down(pd, off, 16);
    }
    if ((lane & 15) == 0) {
        int h = lane >> 4;
        al_s[n * 4 + h] = ps;
        al_d[n * 4 + h] = pd;
    }
}

// ---------------- edge softmax + weighted aggregation, one block per dst node ----------------
__global__ __launch_bounds__(256) void agg_kernel(const int* __restrict__ rowptr,
                                                  const int* __restrict__ csr,
                                                  const float* __restrict__ al_s,
                                                  const float* __restrict__ al_d,
                                                  const float* __restrict__ xh,
                                                  float* __restrict__ out) {
    int n = blockIdx.x;
    int tid = threadIdx.x;
    int start = rowptr[n], end = rowptr[n + 1];
    __shared__ float4 red4[256];
    __shared__ float s_w[256];
    __shared__ int s_src[64];
    __shared__ float4 s_stat[2];

    float ad0 = al_d[n * 4 + 0], ad1 = al_d[n * 4 + 1];
    float ad2 = al_d[n * 4 + 2], ad3 = al_d[n * 4 + 3];

    // pass 1: per-head max
    float m0 = -1e30f, m1 = -1e30f, m2 = -1e30f, m3 = -1e30f;
    for (int i = start + tid; i < end; i += 256) {
        int s = csr[i];
        float e0 = al_s[s * 4 + 0] + ad0; e0 = e0 > 0.f ? e0 : NEG * e0;
        float e1 = al_s[s * 4 + 1] + ad1; e1 = e1 > 0.f ? e1 : NEG * e1;
        float e2 = al_s[s * 4 + 2] + ad2; e2 = e2 > 0.f ? e2 : NEG * e2;
        float e3 = al_s[s * 4 + 3] + ad3; e3 = e3 > 0.f ? e3 : NEG * e3;
        m0 = fmaxf(m0, e0); m1 = fmaxf(m1, e1); m2 = fmaxf(m2, e2); m3 = fmaxf(m3, e3);
    }
    red4[tid] = make_float4(m0, m1, m2, m3);
    __syncthreads();
    for (int o = 128; o > 0; o >>= 1) {
        if (tid < o) {
            float4 a = red4[tid], b = red4[tid + o];
            a.x = fmaxf(a.x, b.x); a.y = fmaxf(a.y, b.y);
            a.z = fmaxf(a.z, b.z); a.w = fmaxf(a.w, b.w);
            red4[tid] = a;
        }
        __syncthreads();
    }
    if (tid == 0) s_stat[0] = red4[0];
    __syncthreads();
    float4 mv = s_stat[0];
    __syncthreads();

    // pass 2: per-head sum of exp
    float s0 = 0.f, s1 = 0.f, s2 = 0.f, s3 = 0.f;
    for (int i = start + tid; i < end; i += 256) {
        int s = csr[i];
        float e0 = al_s[s * 4 + 0] + ad0; e0 = e0 > 0.f ? e0 : NEG * e0;
        float e1 = al_s[s * 4 + 1] + ad1; e1 = e1 > 0.f ? e1 : NEG * e1;
        float e2 = al_s[s * 4 + 2] + ad2; e2 = e2 > 0.f ? e2 : NEG * e2;
        float e3 = al_s[s * 4 + 3] + ad3; e3 = e3 > 0.f ? e3 : NEG * e3;
        s0 += __expf(e0 - mv.x); s1 += __expf(e1 - mv.y);
        s2 += __expf(e2 - mv.z); s3 += __expf(e3 - mv.w);
    }
    red4[tid] = make_float4(s0, s1, s2, s3);
    __syncthreads();
    for (int o = 128; o > 0; o >>= 1) {
        if (tid < o) {
            float4 a = red4[tid], b = red4[tid + o];
            a.x += b.x; a.y += b.y; a.z += b.z; a.w += b.w;
            red4[tid] = a;
        }
        __syncthreads();
    }
    if (tid == 0) {
        float4 d = red4[0];
        s_stat[1] = make_float4(1.f / d.x, 1.f / d.y, 1.f / d.z, 1.f / d.w);
    }
    __syncthreads();
    float4 inv = s_stat[1];

    int myh = tid >> 6;
    float md   = (myh == 0) ? mv.x : (myh == 1) ? mv.y : (myh == 2) ? mv.z : mv.w;
    float invd = (myh == 0) ? inv.x : (myh == 1) ? inv.y : (myh == 2) ? inv.z : inv.w;
    float adh  = (myh == 0) ? ad0 : (myh == 1) ? ad1 : (myh == 2) ? ad2 : ad3;

    // pass 3: weighted accumulate, 64-edge chunks
    float acc = 0.f;
    for (int cb = start; cb < end; cb += 64) {
        int c = min(64, end - cb);
        int j = tid & 63;
        __syncthreads();
        if (j < c) {
            int s = csr[cb + j];
            if (tid < 64) s_src[j] = s;
            float e = al_s[s * 4 + myh] + adh;
            e = e > 0.f ? e : NEG * e;
            s_w[tid] = __expf(e - md) * invd;
        }
        __syncthreads();
        for (int jj = 0; jj < c; jj++)
            acc += s_w[myh * 64 + jj] * xh[(size_t)s_src[jj] * HID + tid];
    }
    out[(size_t)n * HID + tid] = acc;
}

// ---------------- LayerNorm + ReLU + residual add ----------------
__global__ __launch_bounds__(256) void ln_relu_add_kernel(const float* __restrict__ hin,
                                                          const float* __restrict__ bgat,
                                                          const float* __restrict__ g,
                                                          const float* __restrict__ bb,
                                                          float* __restrict__ h) {
    int n = blockIdx.x, t = threadIdx.x;
    float v = hin[(size_t)n * HID + t] + bgat[t];
    __shared__ float red[256];
    __shared__ float s_mu, s_var;
    red[t] = v;
    __syncthreads();
    for (int o = 128; o > 0; o >>= 1) {
        if (t < o) red[t] += red[t + o];
        __syncthreads();
    }
    if (t == 0) s_mu = red[0] * (1.f / HID);
    __syncthreads();
    float mu = s_mu;
    float d = v - mu;
    __syncthreads();
    red[t] = d * d;
    __syncthreads();
    for (int o = 128; o > 0; o >>= 1) {
        if (t < o) red[t] += red[t + o];
        __syncthreads();
    }
    if (t == 0) s_var = red[0] * (1.f / HID);
    __syncthreads();
    float o = d * rsqrtf(s_var + LNEPS) * g[t] + bb[t];
    o = fmaxf(o, 0.f);
    h[(size_t)n * HID + t] += o;
}

// ---------------- final tiny GEMM: out[n][c] = mid[n][:] @ W_c2 + b_c2 ----------------
__global__ void cls2_kernel(const float* __restrict__ mid, const float* __restrict__ W,
                            const float* __restrict__ bias, float* __restrict__ out) {
    int idx = blockIdx.x * 256 + threadIdx.x;
    if (idx >= NN * NCLS) return;
    int n = idx / NCLS, c = idx % NCLS;
    const float* row = mid + (size_t)n * (HID / 2);
    float acc = bias[c];
#pragma unroll 8
    for (int k = 0; k < HID / 2; k++) acc += row[k] * W[k * NCLS + c];
    out[idx] = acc;
}

extern "C" void kernel_launch(void* const* d_in, const int* in_sizes, int n_in,
                              void* d_out, int out_size, void* d_ws, size_t ws_size,
                              hipStream_t stream) {
    const float* x    = (const float*)d_in[0];
    const int*   ei   = (const int*)d_in[1];
    const float* W_in = (const float*)d_in[2];
    const float* b_in = (const float*)d_in[3];
    const float* W_gat[2]   = {(const float*)d_in[4],  (const float*)d_in[10]};
    const float* att_src[2] = {(const float*)d_in[5],  (const float*)d_in[11]};
    const float* att_dst[2] = {(const float*)d_in[6],  (const float*)d_in[12]};
    const float* b_gat[2]   = {(const float*)d_in[7],  (const float*)d_in[13]};
    const float* ln_g[2]    = {(const float*)d_in[8],  (const float*)d_in[14]};
    const float* ln_b[2]    = {(const float*)d_in[9],  (const float*)d_in[15]};
    const float* W_c1 = (const float*)d_in[16];
    const float* b_c1 = (const float*)d_in[17];
    const float* W_c2 = (const float*)d_in[18];
    const float* b_c2 = (const float*)d_in[19];

    char* ws = (char*)d_ws;
    size_t off = 0;
    auto alloc = [&](size_t bytes) -> void* {
        void* p = ws + off;
        off += (bytes + 255) & ~(size_t)255;
        return p;
    };
    float* h    = (float*)alloc((size_t)NN * HID * 4);
    float* xh   = (float*)alloc((size_t)NN * HID * 4);
    float* hnew = (float*)alloc((size_t)NN * HID * 4);
    float* al_s = (float*)alloc((size_t)NN * HEADS * 4);
    float* al_d = (float*)alloc((size_t)NN * HEADS * 4);
    int* rowptr = (int*)alloc((size_t)(NN + 1) * 4);
    int* cursor = (int*)alloc((size_t)NN * 4);
    int* csr    = (int*)alloc((size_t)(EE + NN) * 4);
    float* mid  = xh;  // reuse after GAT layers

    const int* srcv = ei;
    const int* dstv = ei + EE;

    // CSR build (dst -> incoming srcs, incl. self loops)
    init_cnt_kernel<<<(NN + 255) / 256, 256, 0, stream>>>(cursor);
    count_edges_kernel<<<(EE + 255) / 256, 256, 0, stream>>>(dstv, cursor);
    scan_excl_kernel<<<1, 1024, 0, stream>>>(cursor, rowptr, NN);
    copy_i32_kernel<<<(NN + 255) / 256, 256, 0, stream>>>(rowptr, cursor, NN);
    fill_self_kernel<<<(NN + 255) / 256, 256, 0, stream>>>(cursor, csr);
    scatter_edges_kernel<<<(EE + 255) / 256, 256, 0, stream>>>(srcv, dstv, cursor, csr);

    // h = relu(x @ W_in + b_in)
    gemm_kernel<1><<<dim3((NN + 63) / 64, HID / 64), 256, 0, stream>>>(
        x, W_in, b_in, h, NN, INDIM, HID);

    for (int l = 0; l < 2; l++) {
        gemm_kernel<0><<<dim3((NN + 63) / 64, HID / 64), 256, 0, stream>>>(
            h, W_gat[l], nullptr, xh, NN, HID, HID);
        proj_al_kernel<<<(NN + 3) / 4, 256, 0, stream>>>(xh, att_src[l], att_dst[l], al_s, al_d);
        agg_kernel<<<NN, 256, 0, stream>>>(rowptr, csr, al_s, al_d, xh, hnew);
        ln_relu_add_kernel<<<NN, 256, 0, stream>>>(hnew, b_gat[l], ln_g[l], ln_b[l], h);
    }

    // classifier
    gemm_kernel<1><<<dim3((NN + 63) / 64, (HID / 2) / 64), 256, 0, stream>>>(
        h, W_c1, b_c1, mid, NN, HID, HID / 2);
    cls2_kernel<<<(NN * NCLS + 255) / 256, 256, 0, stream>>>(mid, W_c2, b_c2, (float*)d_out);
}

// Round 2
// 1404.555 us; speedup vs baseline: 1.5238x; 1.5238x over previous
//
#include <hip/hip_runtime.h>

#define NN 50000
#define EE 1600000
#define INDIM 1280
#define HID 256
#define HEADS 4
#define DHD 64
#define NCLS 6
#define NEG 0.2f
#define LNEPS 1e-5f

typedef __attribute__((ext_vector_type(8))) short short8;
typedef __attribute__((ext_vector_type(4))) float floatx4;

__device__ __forceinline__ unsigned short f2b(float f) {
    unsigned int u = __float_as_uint(f);
    u += 0x7FFF + ((u >> 16) & 1);
    return (unsigned short)(u >> 16);
}
__device__ __forceinline__ float b2f(unsigned short b) {
    return __uint_as_float(((unsigned int)b) << 16);
}

// ---------------- CSR build ----------------
__global__ void init_cnt_kernel(int* __restrict__ cnt) {
    int n = blockIdx.x * 256 + threadIdx.x;
    if (n < NN) cnt[n] = 1;  // self loop
}

__global__ void count_edges_kernel(const int* __restrict__ dst, int* __restrict__ cnt) {
    int e = blockIdx.x * 256 + threadIdx.x;
    if (e < EE) atomicAdd(&cnt[dst[e]], 1);
}

// single-block exclusive scan (shuffle-based, 4 barriers per 1024 chunk)
__global__ __launch_bounds__(1024) void scan_excl_kernel(const int* __restrict__ cnt,
                                                         int* __restrict__ rowptr, int n) {
    __shared__ int wsum[16];
    __shared__ int carry_s;
    int tid = threadIdx.x;
    int lane = tid & 63, wv = tid >> 6;
    if (tid == 0) { carry_s = 0; rowptr[0] = 0; }
    __syncthreads();
    for (int base = 0; base < n; base += 1024) {
        int i = base + tid;
        int v = (i < n) ? cnt[i] : 0;
        int s = v;
#pragma unroll
        for (int off = 1; off < 64; off <<= 1) {
            int t = __shfl_up(s, off, 64);
            if (lane >= off) s += t;
        }
        if (lane == 63) wsum[wv] = s;
        __syncthreads();
        if (wv == 0 && lane < 16) {
            int ws = wsum[lane];
#pragma unroll
            for (int off = 1; off < 16; off <<= 1) {
                int t = __shfl_up(ws, off, 16);
                if (lane >= off) ws += t;
            }
            wsum[lane] = ws;
        }
        __syncthreads();
        int add = (wv > 0 ? wsum[wv - 1] : 0) + carry_s;
        if (i < n) rowptr[i + 1] = add + s;  // inclusive scan -> rowptr[i+1]
        __syncthreads();
        if (tid == 1023) carry_s += wsum[15];
        __syncthreads();
    }
}

__global__ void copy_i32_kernel(const int* __restrict__ src, int* __restrict__ dst, int n) {
    int i = blockIdx.x * 256 + threadIdx.x;
    if (i < n) dst[i] = src[i];
}

__global__ void fill_self_kernel(int* __restrict__ cursor, int* __restrict__ csr) {
    int n = blockIdx.x * 256 + threadIdx.x;
    if (n < NN) {
        int pos = atomicAdd(&cursor[n], 1);
        csr[pos] = n;
    }
}

__global__ void scatter_edges_kernel(const int* __restrict__ src, const int* __restrict__ dst,
                                     int* __restrict__ cursor, int* __restrict__ csr) {
    int e = blockIdx.x * 256 + threadIdx.x;
    if (e < EE) {
        int d = dst[e];
        int pos = atomicAdd(&cursor[d], 1);
        csr[pos] = src[e];
    }
}

// ---------------- weight transpose+convert: W[K][N] fp32 -> WT[N][K] bf16 ----------------
__global__ void transpose_w_kernel(const float* __restrict__ W, unsigned short* __restrict__ WT,
                                   int K, int N) {
    int idx = blockIdx.x * 256 + threadIdx.x;
    if (idx >= K * N) return;
    int n = idx / K, k = idx % K;  // write-coalesced
    WT[idx] = f2b(W[(size_t)k * N + n]);
}

// ---------------- bf16 MFMA GEMM ----------------
// C[M,N] = act(A[M,K] @ BT[N,K]^T + bias). BM=128, BN=64, BK=64, 256 threads (4 waves).
// LDS holds fragments in MFMA lane order: block(tile16, kstep32) -> 64 lanes x 16B.
template <int AF32, int ACT, int WF32, int WB16>
__global__ __launch_bounds__(256) void mgemm_kernel(const float* __restrict__ Af,
                                                    const unsigned short* __restrict__ Ab,
                                                    const unsigned short* __restrict__ BT,
                                                    const float* __restrict__ bias,
                                                    float* __restrict__ Cf,
                                                    unsigned short* __restrict__ Cb,
                                                    int M, int K, int N) {
    __shared__ __align__(16) unsigned short Als[16 * 512];  // 8 mtiles x 2 ksteps x 512
    __shared__ __align__(16) unsigned short Bls[8 * 512];   // 4 ntiles x 2 ksteps x 512
    int tid = threadIdx.x;
    int wv = tid >> 6, ln = tid & 63;
    int n0 = blockIdx.x * 64, m0 = blockIdx.y * 128;

    floatx4 acc[2][4] = {};

    for (int k0 = 0; k0 < K; k0 += 64) {
        // stage A: 1024 chunks of 8 bf16
#pragma unroll
        for (int i = 0; i < 4; i++) {
            int e = tid + i * 256;
            int r = e >> 3, c8 = e & 7;
            int gm = m0 + r;
            int4 v = {0, 0, 0, 0};
            if (gm < M) {
                if (AF32) {
                    const float* s = Af + (size_t)gm * K + k0 + c8 * 8;
                    float4 f0 = *(const float4*)s;
                    float4 f1 = *(const float4*)(s + 4);
                    unsigned short u[8] = {f2b(f0.x), f2b(f0.y), f2b(f0.z), f2b(f0.w),
                                           f2b(f1.x), f2b(f1.y), f2b(f1.z), f2b(f1.w)};
                    v = *(const int4*)u;
                } else {
                    v = *(const int4*)(Ab + (size_t)gm * K + k0 + c8 * 8);
                }
            }
            int blk = (r >> 4) * 2 + (c8 >> 2);
            int lslot = (r & 15) + 16 * (c8 & 3);
            *(int4*)&Als[blk * 512 + lslot * 8] = v;
        }
        // stage B: 512 chunks
#pragma unroll
        for (int i = 0; i < 2; i++) {
            int e = tid + i * 256;
            int r = e >> 3, c8 = e & 7;
            int4 v = *(const int4*)(BT + (size_t)(n0 + r) * K + k0 + c8 * 8);
            int blk = (r >> 4) * 2 + (c8 >> 2);
            int lslot = (r & 15) + 16 * (c8 & 3);
            *(int4*)&Bls[blk * 512 + lslot * 8] = v;
        }
        __syncthreads();
#pragma unroll
        for (int ks = 0; ks < 2; ks++) {
            short8 a0 = *(const short8*)&Als[((wv * 2 + 0) * 2 + ks) * 512 + ln * 8];
            short8 a1 = *(const short8*)&Als[((wv * 2 + 1) * 2 + ks) * 512 + ln * 8];
#pragma unroll
            for (int nt = 0; nt < 4; nt++) {
                short8 b = *(const short8*)&Bls[(nt * 2 + ks) * 512 + ln * 8];
                acc[0][nt] = __builtin_amdgcn_mfma_f32_16x16x32_bf16(a0, b, acc[0][nt], 0, 0, 0);
                acc[1][nt] = __builtin_amdgcn_mfma_f32_16x16x32_bf16(a1, b, acc[1][nt], 0, 0, 0);
            }
        }
        __syncthreads();
    }

    // epilogue: C/D layout col=lane&15, row=(lane>>4)*4+reg
#pragma unroll
    for (int ms = 0; ms < 2; ms++) {
#pragma unroll
        for (int nt = 0; nt < 4; nt++) {
            int col = n0 + nt * 16 + (ln & 15);
            int rb = m0 + (wv * 2 + ms) * 16 + (ln >> 4) * 4;
            float bi = bias ? bias[col] : 0.f;
#pragma unroll
            for (int r = 0; r < 4; r++) {
                int row = rb + r;
                if (row < M) {
                    float v = acc[ms][nt][r] + bi;
                    if (ACT) v = fmaxf(v, 0.f);
                    if (WF32) Cf[(size_t)row * N + col] = v;
                    if (WB16) Cb[(size_t)row * N + col] = f2b(v);
                }
            }
        }
    }
}

// ---------------- attention logits from bf16 xh ----------------
__global__ __launch_bounds__(256) void proj_al_kernel(const unsigned short* __restrict__ xhb,
                                                      const float* __restrict__ a_src,
                                                      const float* __restrict__ a_dst,
                                                      float* __restrict__ al_s,
                                                      float* __restrict__ al_d) {
    int n = blockIdx.x * 4 + (threadIdx.x >> 6);
    if (n >= NN) return;
    int lane = threadIdx.x & 63;
    ushort4 v4 = ((const ushort4*)(xhb + (size_t)n * HID))[lane];  // positions lane*4..+3
    int base = (lane >> 4) * 64 + (lane & 15) * 4;
    float4 as4 = *(const float4*)&a_src[base];
    float4 ad4 = *(const float4*)&a_dst[base];
    float x0 = b2f(v4.x), x1 = b2f(v4.y), x2 = b2f(v4.z), x3 = b2f(v4.w);
    float ps = x0 * as4.x + x1 * as4.y + x2 * as4.z + x3 * as4.w;
    float pd = x0 * ad4.x + x1 * ad4.y + x2 * ad4.z + x3 * ad4.w;
#pragma unroll
    for (int off = 8; off > 0; off >>= 1) {
        ps += __shfl_down(ps, off, 16);
        pd += __shfl_down(pd, off, 16);
    }
    if ((lane & 15) == 0) {
        int h = lane >> 4;
        al_s[n * 4 + h] = ps;
        al_d[n * 4 + h] = pd;
    }
}

// ---------------- edge softmax + aggregation + LN + ReLU + residual, one block per dst ----------------
__global__ __launch_bounds__(256) void agg_ln_kernel(const int* __restrict__ rowptr,
                                                     const int* __restrict__ csr,
                                                     const float* __restrict__ al_s,
                                                     const float* __restrict__ al_d,
                                                     const unsigned short* __restrict__ xhb,
                                                     const float* __restrict__ bgat,
                                                     const float* __restrict__ g,
                                                     const float* __restrict__ bb,
                                                     float* __restrict__ h,
                                                     unsigned short* __restrict__ hb) {
    int n = blockIdx.x;
    int tid = threadIdx.x;
    int start = rowptr[n], end = rowptr[n + 1];
    __shared__ float4 red4[256];
    __shared__ float s_w[256];
    __shared__ int s_src[64];
    __shared__ float4 s_stat[2];
    __shared__ float s_mu, s_var;

    float ad0 = al_d[n * 4 + 0], ad1 = al_d[n * 4 + 1];
    float ad2 = al_d[n * 4 + 2], ad3 = al_d[n * 4 + 3];

    // pass 1: per-head max
    float m0 = -1e30f, m1 = -1e30f, m2 = -1e30f, m3 = -1e30f;
    for (int i = start + tid; i < end; i += 256) {
        int s = csr[i];
        float e0 = al_s[s * 4 + 0] + ad0; e0 = e0 > 0.f ? e0 : NEG * e0;
        float e1 = al_s[s * 4 + 1] + ad1; e1 = e1 > 0.f ? e1 : NEG * e1;
        float e2 = al_s[s * 4 + 2] + ad2; e2 = e2 > 0.f ? e2 : NEG * e2;
        float e3 = al_s[s * 4 + 3] + ad3; e3 = e3 > 0.f ? e3 : NEG * e3;
        m0 = fmaxf(m0, e0); m1 = fmaxf(m1, e1); m2 = fmaxf(m2, e2); m3 = fmaxf(m3, e3);
    }
    red4[tid] = make_float4(m0, m1, m2, m3);
    __syncthreads();
    for (int o = 128; o > 0; o >>= 1) {
        if (tid < o) {
            float4 a = red4[tid], b = red4[tid + o];
            a.x = fmaxf(a.x, b.x); a.y = fmaxf(a.y, b.y);
            a.z = fmaxf(a.z, b.z); a.w = fmaxf(a.w, b.w);
            red4[tid] = a;
        }
        __syncthreads();
    }
    if (tid == 0) s_stat[0] = red4[0];
    __syncthreads();
    float4 mv = s_stat[0];
    __syncthreads();

    // pass 2: per-head sum of exp
    float s0 = 0.f, s1 = 0.f, s2 = 0.f, s3 = 0.f;
    for (int i = start + tid; i < end; i += 256) {
        int s = csr[i];
        float e0 = al_s[s * 4 + 0] + ad0; e0 = e0 > 0.f ? e0 : NEG * e0;
        float e1 = al_s[s * 4 + 1] + ad1; e1 = e1 > 0.f ? e1 : NEG * e1;
        float e2 = al_s[s * 4 + 2] + ad2; e2 = e2 > 0.f ? e2 : NEG * e2;
        float e3 = al_s[s * 4 + 3] + ad3; e3 = e3 > 0.f ? e3 : NEG * e3;
        s0 += __expf(e0 - mv.x); s1 += __expf(e1 - mv.y);
        s2 += __expf(e2 - mv.z); s3 += __expf(e3 - mv.w);
    }
    red4[tid] = make_float4(s0, s1, s2, s3);
    __syncthreads();
    for (int o = 128; o > 0; o >>= 1) {
        if (tid < o) {
            float4 a = red4[tid], b = red4[tid + o];
            a.x += b.x; a.y += b.y; a.z += b.z; a.w += b.w;
            red4[tid] = a;
        }
        __syncthreads();
    }
    if (tid == 0) {
        float4 d = red4[0];
        s_stat[1] = make_float4(1.f / d.x, 1.f / d.y, 1.f / d.z, 1.f / d.w);
    }
    __syncthreads();
    float4 inv = s_stat[1];

    int myh = tid >> 6;
    float md   = (myh == 0) ? mv.x : (myh == 1) ? mv.y : (myh == 2) ? mv.z : mv.w;
    float invd = (myh == 0) ? inv.x : (myh == 1) ? inv.y : (myh == 2) ? inv.z : inv.w;
    float adh  = (myh == 0) ? ad0 : (myh == 1) ? ad1 : (myh == 2) ? ad2 : ad3;

    // pass 3: weighted accumulate of bf16 xh rows
    float acc = 0.f;
    for (int cb = start; cb < end; cb += 64) {
        int c = min(64, end - cb);
        int j = tid & 63;
        __syncthreads();
        if (j < c) {
            int s = csr[cb + j];
            if (tid < 64) s_src[j] = s;
            float e = al_s[s * 4 + myh] + adh;
            e = e > 0.f ? e : NEG * e;
            s_w[tid] = __expf(e - md) * invd;
        }
        __syncthreads();
        for (int jj = 0; jj < c; jj++)
            acc += s_w[myh * 64 + jj] * b2f(xhb[(size_t)s_src[jj] * HID + tid]);
    }

    // fused LayerNorm + ReLU + residual
    float v = acc + bgat[tid];
    float* redf = (float*)red4;
    __syncthreads();
    redf[tid] = v;
    __syncthreads();
    for (int o = 128; o > 0; o >>= 1) {
        if (tid < o) redf[tid] += redf[tid + o];
        __syncthreads();
    }
    if (tid == 0) s_mu = redf[0] * (1.f / HID);
    __syncthreads();
    float mu = s_mu;
    float d = v - mu;
    __syncthreads();
    redf[tid] = d * d;
    __syncthreads();
    for (int o = 128; o > 0; o >>= 1) {
        if (tid < o) redf[tid] += redf[tid + o];
        __syncthreads();
    }
    if (tid == 0) s_var = redf[0] * (1.f / HID);
    __syncthreads();
    float o = d * rsqrtf(s_var + LNEPS) * g[tid] + bb[tid];
    o = fmaxf(o, 0.f);
    size_t idx = (size_t)n * HID + tid;
    float nh = h[idx] + o;
    h[idx] = nh;
    hb[idx] = f2b(nh);
}

// ---------------- final tiny GEMM: out[n][c] = mid[n][:] @ W_c2 + b_c2 ----------------
__global__ void cls2_kernel(const float* __restrict__ mid, const float* __restrict__ W,
                            const float* __restrict__ bias, float* __restrict__ out) {
    int idx = blockIdx.x * 256 + threadIdx.x;
    if (idx >= NN * NCLS) return;
    int n = idx / NCLS, c = idx % NCLS;
    const float* row = mid + (size_t)n * (HID / 2);
    float acc = bias[c];
#pragma unroll 8
    for (int k = 0; k < HID / 2; k++) acc += row[k] * W[k * NCLS + c];
    out[idx] = acc;
}

extern "C" void kernel_launch(void* const* d_in, const int* in_sizes, int n_in,
                              void* d_out, int out_size, void* d_ws, size_t ws_size,
                              hipStream_t stream) {
    const float* x    = (const float*)d_in[0];
    const int*   ei   = (const int*)d_in[1];
    const float* W_in = (const float*)d_in[2];
    const float* b_in = (const float*)d_in[3];
    const float* W_gat[2]   = {(const float*)d_in[4],  (const float*)d_in[10]};
    const float* att_src[2] = {(const float*)d_in[5],  (const float*)d_in[11]};
    const float* att_dst[2] = {(const float*)d_in[6],  (const float*)d_in[12]};
    const float* b_gat[2]   = {(const float*)d_in[7],  (const float*)d_in[13]};
    const float* ln_g[2]    = {(const float*)d_in[8],  (const float*)d_in[14]};
    const float* ln_b[2]    = {(const float*)d_in[9],  (const float*)d_in[15]};
    const float* W_c1 = (const float*)d_in[16];
    const float* b_c1 = (const float*)d_in[17];
    const float* W_c2 = (const float*)d_in[18];
    const float* b_c2 = (const float*)d_in[19];

    char* ws = (char*)d_ws;
    size_t off = 0;
    auto alloc = [&](size_t bytes) -> void* {
        void* p = ws + off;
        off += (bytes + 255) & ~(size_t)255;
        return p;
    };
    float*          h    = (float*)alloc((size_t)NN * HID * 4);
    unsigned short* hb   = (unsigned short*)alloc((size_t)NN * HID * 2);
    unsigned short* xhb  = (unsigned short*)alloc((size_t)NN * HID * 2);  // reused as mid fp32
    float* al_s = (float*)alloc((size_t)NN * HEADS * 4);
    float* al_d = (float*)alloc((size_t)NN * HEADS * 4);
    int* rowptr = (int*)alloc((size_t)(NN + 1) * 4);
    int* cursor = (int*)alloc((size_t)NN * 4);
    int* csr    = (int*)alloc((size_t)(EE + NN) * 4);
    unsigned short* WinT = (unsigned short*)alloc((size_t)HID * INDIM * 2);
    unsigned short* WgT0 = (unsigned short*)alloc((size_t)HID * HID * 2);
    unsigned short* WgT1 = (unsigned short*)alloc((size_t)HID * HID * 2);
    unsigned short* Wc1T = (unsigned short*)alloc((size_t)(HID / 2) * HID * 2);
    unsigned short* WgT[2] = {WgT0, WgT1};
    float* mid = (float*)xhb;

    const int* srcv = ei;
    const int* dstv = ei + EE;

    // weight transposes (fp32 -> bf16 [N][K])
    transpose_w_kernel<<<(INDIM * HID + 255) / 256, 256, 0, stream>>>(W_in, WinT, INDIM, HID);
    transpose_w_kernel<<<(HID * HID + 255) / 256, 256, 0, stream>>>(W_gat[0], WgT0, HID, HID);
    transpose_w_kernel<<<(HID * HID + 255) / 256, 256, 0, stream>>>(W_gat[1], WgT1, HID, HID);
    transpose_w_kernel<<<(HID * (HID / 2) + 255) / 256, 256, 0, stream>>>(W_c1, Wc1T, HID, HID / 2);

    // CSR build (dst -> incoming srcs, incl. self loops)
    init_cnt_kernel<<<(NN + 255) / 256, 256, 0, stream>>>(cursor);
    count_edges_kernel<<<(EE + 255) / 256, 256, 0, stream>>>(dstv, cursor);
    scan_excl_kernel<<<1, 1024, 0, stream>>>(cursor, rowptr, NN);
    copy_i32_kernel<<<(NN + 255) / 256, 256, 0, stream>>>(rowptr, cursor, NN);
    fill_self_kernel<<<(NN + 255) / 256, 256, 0, stream>>>(cursor, csr);
    scatter_edges_kernel<<<(EE + 255) / 256, 256, 0, stream>>>(srcv, dstv, cursor, csr);

    int MB = (NN + 127) / 128;  // 391

    // h = relu(x @ W_in + b_in), writes fp32 h + bf16 hb
    mgemm_kernel<1, 1, 1, 1><<<dim3(HID / 64, MB), 256, 0, stream>>>(
        x, nullptr, WinT, b_in, h, hb, NN, INDIM, HID);

    for (int l = 0; l < 2; l++) {
        // xh = h @ W_gat (bf16 out)
        mgemm_kernel<0, 0, 0, 1><<<dim3(HID / 64, MB), 256, 0, stream>>>(
            nullptr, hb, WgT[l], nullptr, nullptr, xhb, NN, HID, HID);
        proj_al_kernel<<<(NN + 3) / 4, 256, 0, stream>>>(xhb, att_src[l], att_dst[l], al_s, al_d);
        agg_ln_kernel<<<NN, 256, 0, stream>>>(rowptr, csr, al_s, al_d, xhb,
                                              b_gat[l], ln_g[l], ln_b[l], h, hb);
    }

    // classifier
    mgemm_kernel<0, 1, 1, 0><<<dim3((HID / 2) / 64, MB), 256, 0, stream>>>(
        nullptr, hb, Wc1T, b_c1, mid, nullptr, NN, HID, HID / 2);
    cls2_kernel<<<(NN * NCLS + 255) / 256, 256, 0, stream>>>(mid, W_c2, b_c2, (float*)d_out);
}

// Round 3
// 1110.307 us; speedup vs baseline: 1.9276x; 1.2650x over previous
//
#include <hip/hip_runtime.h>

#define NN 50000
#define EE 1600000
#define INDIM 1280
#define HID 256
#define HEADS 4
#define DHD 64
#define NCLS 6
#define NEG 0.2f
#define LNEPS 1e-5f

typedef __attribute__((ext_vector_type(8))) short short8;
typedef __attribute__((ext_vector_type(4))) float floatx4;

__device__ __forceinline__ unsigned short f2b(float f) {
    unsigned int u = __float_as_uint(f);
    u += 0x7FFF + ((u >> 16) & 1);
    return (unsigned short)(u >> 16);
}
__device__ __forceinline__ float b2f(unsigned short b) {
    return __uint_as_float(((unsigned int)b) << 16);
}

// ---------------- CSR build ----------------
__global__ void init_cnt_kernel(int* __restrict__ cnt) {
    int n = blockIdx.x * 256 + threadIdx.x;
    if (n < NN) cnt[n] = 1;  // self loop
}

__global__ void count_edges_kernel(const int* __restrict__ dst, int* __restrict__ cnt) {
    int e = blockIdx.x * 256 + threadIdx.x;
    if (e < EE) atomicAdd(&cnt[dst[e]], 1);
}

// scan stage 1: per-1024-chunk inclusive scan + chunk totals
__global__ __launch_bounds__(1024) void scan1_kernel(const int* __restrict__ cnt,
                                                     int* __restrict__ scanned,
                                                     int* __restrict__ chtot, int n) {
    __shared__ int wsum[16];
    int tid = threadIdx.x, lane = tid & 63, wv = tid >> 6;
    int i = blockIdx.x * 1024 + tid;
    int s = (i < n) ? cnt[i] : 0;
#pragma unroll
    for (int off = 1; off < 64; off <<= 1) {
        int t = __shfl_up(s, off, 64);
        if (lane >= off) s += t;
    }
    if (lane == 63) wsum[wv] = s;
    __syncthreads();
    if (tid < 16) {
        int ws = wsum[tid];
#pragma unroll
        for (int off = 1; off < 16; off <<= 1) {
            int t = __shfl_up(ws, off, 16);
            if (tid >= off) ws += t;
        }
        wsum[tid] = ws;
    }
    __syncthreads();
    s += (wv > 0) ? wsum[wv - 1] : 0;
    if (i < n) scanned[i] = s;
    if (tid == 1023) chtot[blockIdx.x] = s;
}

// scan stage 2: inclusive scan over <=64 chunk totals (one wave)
__global__ void scan2_kernel(int* __restrict__ chtot, int nch) {
    int lane = threadIdx.x;
    int v = (lane < nch) ? chtot[lane] : 0;
#pragma unroll
    for (int off = 1; off < 64; off <<= 1) {
        int t = __shfl_up(v, off, 64);
        if (lane >= off) v += t;
    }
    if (lane < nch) chtot[lane] = v;
}

// scan stage 3: apply chunk offsets -> rowptr
__global__ void scan3_kernel(const int* __restrict__ scanned, const int* __restrict__ chtot,
                             int* __restrict__ rowptr, int n) {
    int i = blockIdx.x * 256 + threadIdx.x;
    if (i == 0) rowptr[0] = 0;
    if (i < n) {
        int ch = i >> 10;
        rowptr[i + 1] = scanned[i] + (ch ? chtot[ch - 1] : 0);
    }
}

// cursor init + self-loop placement
__global__ void copyfill_kernel(const int* __restrict__ rowptr, int* __restrict__ cursor,
                                int* __restrict__ csr) {
    int n = blockIdx.x * 256 + threadIdx.x;
    if (n < NN) {
        int p = rowptr[n];
        csr[p] = n;
        cursor[n] = p + 1;
    }
}

__global__ void scatter_edges_kernel(const int* __restrict__ src, const int* __restrict__ dst,
                                     int* __restrict__ cursor, int* __restrict__ csr) {
    int e = blockIdx.x * 256 + threadIdx.x;
    if (e < EE) {
        int d = dst[e];
        int pos = atomicAdd(&cursor[d], 1);
        csr[pos] = src[e];
    }
}

// ---------------- weight transpose+convert: W[K][N] fp32 -> WT[N][K] bf16 ----------------
__global__ void transpose_w_kernel(const float* __restrict__ W, unsigned short* __restrict__ WT,
                                   int K, int N) {
    int idx = blockIdx.x * 256 + threadIdx.x;
    if (idx >= K * N) return;
    int n = idx / K, k = idx % K;
    WT[idx] = f2b(W[(size_t)k * N + n]);
}

// ---------------- bf16 MFMA GEMM, BN=64 (classifier) ----------------
template <int AF32, int ACT, int WF32, int WB16>
__global__ __launch_bounds__(256) void mgemm_kernel(const float* __restrict__ Af,
                                                    const unsigned short* __restrict__ Ab,
                                                    const unsigned short* __restrict__ BT,
                                                    const float* __restrict__ bias,
                                                    float* __restrict__ Cf,
                                                    unsigned short* __restrict__ Cb,
                                                    int M, int K, int N) {
    __shared__ __align__(16) unsigned short Als[16 * 512];
    __shared__ __align__(16) unsigned short Bls[8 * 512];
    int tid = threadIdx.x;
    int wv = tid >> 6, ln = tid & 63;
    int n0 = blockIdx.x * 64, m0 = blockIdx.y * 128;

    floatx4 acc[2][4] = {};

    for (int k0 = 0; k0 < K; k0 += 64) {
#pragma unroll
        for (int i = 0; i < 4; i++) {
            int e = tid + i * 256;
            int r = e >> 3, c8 = e & 7;
            int gm = m0 + r;
            int4 v = {0, 0, 0, 0};
            if (gm < M) {
                if (AF32) {
                    const float* s = Af + (size_t)gm * K + k0 + c8 * 8;
                    float4 f0 = *(const float4*)s;
                    float4 f1 = *(const float4*)(s + 4);
                    unsigned short u[8] = {f2b(f0.x), f2b(f0.y), f2b(f0.z), f2b(f0.w),
                                           f2b(f1.x), f2b(f1.y), f2b(f1.z), f2b(f1.w)};
                    v = *(const int4*)u;
                } else {
                    v = *(const int4*)(Ab + (size_t)gm * K + k0 + c8 * 8);
                }
            }
            int blk = (r >> 4) * 2 + (c8 >> 2);
            int lslot = (r & 15) + 16 * (c8 & 3);
            *(int4*)&Als[blk * 512 + lslot * 8] = v;
        }
#pragma unroll
        for (int i = 0; i < 2; i++) {
            int e = tid + i * 256;
            int r = e >> 3, c8 = e & 7;
            int4 v = *(const int4*)(BT + (size_t)(n0 + r) * K + k0 + c8 * 8);
            int blk = (r >> 4) * 2 + (c8 >> 2);
            int lslot = (r & 15) + 16 * (c8 & 3);
            *(int4*)&Bls[blk * 512 + lslot * 8] = v;
        }
        __syncthreads();
#pragma unroll
        for (int ks = 0; ks < 2; ks++) {
            short8 a0 = *(const short8*)&Als[((wv * 2 + 0) * 2 + ks) * 512 + ln * 8];
            short8 a1 = *(const short8*)&Als[((wv * 2 + 1) * 2 + ks) * 512 + ln * 8];
#pragma unroll
            for (int nt = 0; nt < 4; nt++) {
                short8 b = *(const short8*)&Bls[(nt * 2 + ks) * 512 + ln * 8];
                acc[0][nt] = __builtin_amdgcn_mfma_f32_16x16x32_bf16(a0, b, acc[0][nt], 0, 0, 0);
                acc[1][nt] = __builtin_amdgcn_mfma_f32_16x16x32_bf16(a1, b, acc[1][nt], 0, 0, 0);
            }
        }
        __syncthreads();
    }

#pragma unroll
    for (int ms = 0; ms < 2; ms++) {
#pragma unroll
        for (int nt = 0; nt < 4; nt++) {
            int col = n0 + nt * 16 + (ln & 15);
            int rb = m0 + (wv * 2 + ms) * 16 + (ln >> 4) * 4;
            float bi = bias ? bias[col] : 0.f;
#pragma unroll
            for (int r = 0; r < 4; r++) {
                int row = rb + r;
                if (row < M) {
                    float v = acc[ms][nt][r] + bi;
                    if (ACT) v = fmaxf(v, 0.f);
                    if (WF32) Cf[(size_t)row * N + col] = v;
                    if (WB16) Cb[(size_t)row * N + col] = f2b(v);
                }
            }
        }
    }
}

// ---------------- bf16 MFMA GEMM, BN=256 (full width: A read exactly once) ----------------
// BM=64, BN=256, BK=64; wave w covers n-tiles w*4..w*4+3, all 4 m-tiles.
template <int AF32, int ACT, int WF32, int WB16>
__global__ __launch_bounds__(256) void mgemm_n256_kernel(const float* __restrict__ Af,
                                                         const unsigned short* __restrict__ Ab,
                                                         const unsigned short* __restrict__ BT,
                                                         const float* __restrict__ bias,
                                                         float* __restrict__ Cf,
                                                         unsigned short* __restrict__ Cb,
                                                         int M, int K) {
    __shared__ __align__(16) unsigned short Als[8 * 512];    // 4 mtiles x 2 ks
    __shared__ __align__(16) unsigned short Bls[32 * 512];   // 16 ntiles x 2 ks
    int tid = threadIdx.x;
    int wv = tid >> 6, ln = tid & 63;
    int m0 = blockIdx.x * 64;

    floatx4 acc[4][4] = {};  // [mtile][local ntile]

    for (int k0 = 0; k0 < K; k0 += 64) {
        // stage A: 512 chunks of 8 -> 2 per thread
#pragma unroll
        for (int i = 0; i < 2; i++) {
            int e = tid + i * 256;
            int r = e >> 3, c8 = e & 7;
            int gm = m0 + r;
            int4 v = {0, 0, 0, 0};
            if (gm < M) {
                if (AF32) {
                    const float* s = Af + (size_t)gm * K + k0 + c8 * 8;
                    float4 f0 = *(const float4*)s;
                    float4 f1 = *(const float4*)(s + 4);
                    unsigned short u[8] = {f2b(f0.x), f2b(f0.y), f2b(f0.z), f2b(f0.w),
                                           f2b(f1.x), f2b(f1.y), f2b(f1.z), f2b(f1.w)};
                    v = *(const int4*)u;
                } else {
                    v = *(const int4*)(Ab + (size_t)gm * K + k0 + c8 * 8);
                }
            }
            int blk = (r >> 4) * 2 + (c8 >> 2);
            int lslot = (r & 15) + 16 * (c8 & 3);
            *(int4*)&Als[blk * 512 + lslot * 8] = v;
        }
        // stage B: 2048 chunks -> 8 per thread (full 256 rows of BT)
#pragma unroll
        for (int i = 0; i < 8; i++) {
            int e = tid + i * 256;
            int r = e >> 3, c8 = e & 7;
            int4 v = *(const int4*)(BT + (size_t)r * K + k0 + c8 * 8);
            int blk = (r >> 4) * 2 + (c8 >> 2);
            int lslot = (r & 15) + 16 * (c8 & 3);
            *(int4*)&Bls[blk * 512 + lslot * 8] = v;
        }
        __syncthreads();
#pragma unroll
        for (int ks = 0; ks < 2; ks++) {
            short8 am[4];
#pragma unroll
            for (int mt = 0; mt < 4; mt++)
                am[mt] = *(const short8*)&Als[(mt * 2 + ks) * 512 + ln * 8];
#pragma unroll
            for (int nt4 = 0; nt4 < 4; nt4++) {
                int nt = wv * 4 + nt4;
                short8 b = *(const short8*)&Bls[(nt * 2 + ks) * 512 + ln * 8];
#pragma unroll
                for (int mt = 0; mt < 4; mt++)
                    acc[mt][nt4] = __builtin_amdgcn_mfma_f32_16x16x32_bf16(am[mt], b, acc[mt][nt4], 0, 0, 0);
            }
        }
        __syncthreads();
    }

#pragma unroll
    for (int mt = 0; mt < 4; mt++) {
#pragma unroll
        for (int nt4 = 0; nt4 < 4; nt4++) {
            int col = wv * 64 + nt4 * 16 + (ln & 15);
            int rb = m0 + mt * 16 + (ln >> 4) * 4;
            float bi = bias ? bias[col] : 0.f;
#pragma unroll
            for (int r = 0; r < 4; r++) {
                int row = rb + r;
                if (row < M) {
                    float v = acc[mt][nt4][r] + bi;
                    if (ACT) v = fmaxf(v, 0.f);
                    if (WF32) Cf[(size_t)row * HID + col] = v;
                    if (WB16) Cb[(size_t)row * HID + col] = f2b(v);
                }
            }
        }
    }
}

// ---------------- attention logits from bf16 xh ----------------
__global__ __launch_bounds__(256) void proj_al_kernel(const unsigned short* __restrict__ xhb,
                                                      const float* __restrict__ a_src,
                                                      const float* __restrict__ a_dst,
                                                      float* __restrict__ al_s,
                                                      float* __restrict__ al_d) {
    int n = blockIdx.x * 4 + (threadIdx.x >> 6);
    if (n >= NN) return;
    int lane = threadIdx.x & 63;
    ushort4 v4 = ((const ushort4*)(xhb + (size_t)n * HID))[lane];
    int base = lane * 4;
    float4 as4 = *(const float4*)&a_src[base];
    float4 ad4 = *(const float4*)&a_dst[base];
    float x0 = b2f(v4.x), x1 = b2f(v4.y), x2 = b2f(v4.z), x3 = b2f(v4.w);
    float ps = x0 * as4.x + x1 * as4.y + x2 * as4.z + x3 * as4.w;
    float pd = x0 * ad4.x + x1 * ad4.y + x2 * ad4.z + x3 * ad4.w;
#pragma unroll
    for (int off = 8; off > 0; off >>= 1) {
        ps += __shfl_down(ps, off, 16);
        pd += __shfl_down(pd, off, 16);
    }
    if ((lane & 15) == 0) {
        int h = lane >> 4;
        al_s[n * 4 + h] = ps;
        al_d[n * 4 + h] = pd;
    }
}

// ---------------- wave-per-node: edge softmax + aggregation + LN + ReLU + residual ----------------
// Lane covers 4 columns (ushort4 -> full 512B row per wave load). No max subtraction
// (softmax is shift-invariant; logits are O(1) here, no overflow risk). No LDS, no barriers.
__global__ __launch_bounds__(256) void agg_ln_kernel(const int* __restrict__ rowptr,
                                                     const int* __restrict__ csr,
                                                     const float* __restrict__ al_s,
                                                     const float* __restrict__ al_d,
                                                     const unsigned short* __restrict__ xhb,
                                                     const float* __restrict__ bgat,
                                                     const float* __restrict__ g,
                                                     const float* __restrict__ bb,
                                                     float* __restrict__ h,
                                                     unsigned short* __restrict__ hb) {
    int wv = threadIdx.x >> 6, ln = threadIdx.x & 63;
    int n = blockIdx.x * 4 + wv;
    if (n >= NN) return;
    int start = rowptr[n], end = rowptr[n + 1];
    float4 ad = *(const float4*)&al_d[n * 4];

    // pass A: denominators (4 heads), edges strided over lanes
    float d0 = 0.f, d1 = 0.f, d2 = 0.f, d3 = 0.f;
    for (int i = start + ln; i < end; i += 64) {
        int s = csr[i];
        float4 as = *(const float4*)&al_s[s * 4];
        float e0 = as.x + ad.x; e0 = e0 > 0.f ? e0 : NEG * e0;
        float e1 = as.y + ad.y; e1 = e1 > 0.f ? e1 : NEG * e1;
        float e2 = as.z + ad.z; e2 = e2 > 0.f ? e2 : NEG * e2;
        float e3 = as.w + ad.w; e3 = e3 > 0.f ? e3 : NEG * e3;
        d0 += __expf(e0); d1 += __expf(e1); d2 += __expf(e2); d3 += __expf(e3);
    }
#pragma unroll
    for (int off = 32; off > 0; off >>= 1) {
        d0 += __shfl_xor(d0, off, 64);
        d1 += __shfl_xor(d1, off, 64);
        d2 += __shfl_xor(d2, off, 64);
        d3 += __shfl_xor(d3, off, 64);
    }
    int myh = ln >> 4;
    float invh = 1.f / ((myh == 0) ? d0 : (myh == 1) ? d1 : (myh == 2) ? d2 : d3);
    float adh = (myh == 0) ? ad.x : (myh == 1) ? ad.y : (myh == 2) ? ad.z : ad.w;

    // pass B: weighted row gather; each lane owns columns ln*4..ln*4+3 (same head)
    float a0 = 0.f, a1 = 0.f, a2 = 0.f, a3 = 0.f;
#pragma unroll 2
    for (int i = start; i < end; i++) {
        int s = csr[i];  // wave-uniform -> broadcast
        float e = al_s[s * 4 + myh] + adh;
        e = e > 0.f ? e : NEG * e;
        float w = __expf(e) * invh;
        ushort4 mv = *(const ushort4*)&xhb[(size_t)s * HID + ln * 4];
        a0 = fmaf(w, b2f(mv.x), a0);
        a1 = fmaf(w, b2f(mv.y), a1);
        a2 = fmaf(w, b2f(mv.z), a2);
        a3 = fmaf(w, b2f(mv.w), a3);
    }

    // fused LayerNorm + ReLU + residual (wave-wide over 256 values)
    float4 bg = *(const float4*)&bgat[ln * 4];
    float v0 = a0 + bg.x, v1 = a1 + bg.y, v2 = a2 + bg.z, v3 = a3 + bg.w;
    float ps = v0 + v1 + v2 + v3;
    float ps2 = v0 * v0 + v1 * v1 + v2 * v2 + v3 * v3;
#pragma unroll
    for (int off = 32; off > 0; off >>= 1) {
        ps += __shfl_xor(ps, off, 64);
        ps2 += __shfl_xor(ps2, off, 64);
    }
    float mu = ps * (1.f / HID);
    float var = ps2 * (1.f / HID) - mu * mu;
    float rs = rsqrtf(var + LNEPS);
    float4 gg = *(const float4*)&g[ln * 4];
    float4 bbv = *(const float4*)&bb[ln * 4];
    float o0 = fmaxf((v0 - mu) * rs * gg.x + bbv.x, 0.f);
    float o1 = fmaxf((v1 - mu) * rs * gg.y + bbv.y, 0.f);
    float o2 = fmaxf((v2 - mu) * rs * gg.z + bbv.z, 0.f);
    float o3 = fmaxf((v3 - mu) * rs * gg.w + bbv.w, 0.f);
    size_t idx = (size_t)n * HID + ln * 4;
    float4 hv = *(const float4*)&h[idx];
    float4 nh = make_float4(hv.x + o0, hv.y + o1, hv.z + o2, hv.w + o3);
    *(float4*)&h[idx] = nh;
    ushort4 nb = {f2b(nh.x), f2b(nh.y), f2b(nh.z), f2b(nh.w)};
    *(ushort4*)&hb[idx] = nb;
}

// ---------------- final tiny GEMM: out[n][c] = mid[n][:] @ W_c2 + b_c2 ----------------
__global__ void cls2_kernel(const float* __restrict__ mid, const float* __restrict__ W,
                            const float* __restrict__ bias, float* __restrict__ out) {
    int idx = blockIdx.x * 256 + threadIdx.x;
    if (idx >= NN * NCLS) return;
    int n = idx / NCLS, c = idx % NCLS;
    const float* row = mid + (size_t)n * (HID / 2);
    float acc = bias[c];
#pragma unroll 8
    for (int k = 0; k < HID / 2; k++) acc += row[k] * W[k * NCLS + c];
    out[idx] = acc;
}

extern "C" void kernel_launch(void* const* d_in, const int* in_sizes, int n_in,
                              void* d_out, int out_size, void* d_ws, size_t ws_size,
                              hipStream_t stream) {
    const float* x    = (const float*)d_in[0];
    const int*   ei   = (const int*)d_in[1];
    const float* W_in = (const float*)d_in[2];
    const float* b_in = (const float*)d_in[3];
    const float* W_gat[2]   = {(const float*)d_in[4],  (const float*)d_in[10]};
    const float* att_src[2] = {(const float*)d_in[5],  (const float*)d_in[11]};
    const float* att_dst[2] = {(const float*)d_in[6],  (const float*)d_in[12]};
    const float* b_gat[2]   = {(const float*)d_in[7],  (const float*)d_in[13]};
    const float* ln_g[2]    = {(const float*)d_in[8],  (const float*)d_in[14]};
    const float* ln_b[2]    = {(const float*)d_in[9],  (const float*)d_in[15]};
    const float* W_c1 = (const float*)d_in[16];
    const float* b_c1 = (const float*)d_in[17];
    const float* W_c2 = (const float*)d_in[18];
    const float* b_c2 = (const float*)d_in[19];

    char* ws = (char*)d_ws;
    size_t off = 0;
    auto alloc = [&](size_t bytes) -> void* {
        void* p = ws + off;
        off += (bytes + 255) & ~(size_t)255;
        return p;
    };
    float*          h   = (float*)alloc((size_t)NN * HID * 4);
    unsigned short* hb  = (unsigned short*)alloc((size_t)NN * HID * 2);
    unsigned short* xhb = (unsigned short*)alloc((size_t)NN * HID * 2);
    float* al_s = (float*)alloc((size_t)NN * HEADS * 4);
    float* al_d = (float*)alloc((size_t)NN * HEADS * 4);
    int* rowptr  = (int*)alloc((size_t)(NN + 1) * 4);
    int* cursor  = (int*)alloc((size_t)NN * 4);
    int* csr     = (int*)alloc((size_t)(EE + NN) * 4);
    int* scanned = (int*)alloc((size_t)NN * 4);
    int* chtot   = (int*)alloc(64 * 4);
    unsigned short* WinT = (unsigned short*)alloc((size_t)HID * INDIM * 2);
    unsigned short* WgT0 = (unsigned short*)alloc((size_t)HID * HID * 2);
    unsigned short* WgT1 = (unsigned short*)alloc((size_t)HID * HID * 2);
    unsigned short* Wc1T = (unsigned short*)alloc((size_t)(HID / 2) * HID * 2);
    unsigned short* WgT[2] = {WgT0, WgT1};
    float* mid = (float*)xhb;

    const int* srcv = ei;
    const int* dstv = ei + EE;

    // weight transposes (fp32 -> bf16 [N][K])
    transpose_w_kernel<<<(INDIM * HID + 255) / 256, 256, 0, stream>>>(W_in, WinT, INDIM, HID);
    transpose_w_kernel<<<(HID * HID + 255) / 256, 256, 0, stream>>>(W_gat[0], WgT0, HID, HID);
    transpose_w_kernel<<<(HID * HID + 255) / 256, 256, 0, stream>>>(W_gat[1], WgT1, HID, HID);
    transpose_w_kernel<<<(HID * (HID / 2) + 255) / 256, 256, 0, stream>>>(W_c1, Wc1T, HID, HID / 2);

    // CSR build
    int nch = (NN + 1023) / 1024;
    init_cnt_kernel<<<(NN + 255) / 256, 256, 0, stream>>>(cursor);
    count_edges_kernel<<<(EE + 255) / 256, 256, 0, stream>>>(dstv, cursor);
    scan1_kernel<<<nch, 1024, 0, stream>>>(cursor, scanned, chtot, NN);
    scan2_kernel<<<1, 64, 0, stream>>>(chtot, nch);
    scan3_kernel<<<(NN + 255) / 256, 256, 0, stream>>>(scanned, chtot, rowptr, NN);
    copyfill_kernel<<<(NN + 255) / 256, 256, 0, stream>>>(rowptr, cursor, csr);
    scatter_edges_kernel<<<(EE + 255) / 256, 256, 0, stream>>>(srcv, dstv, cursor, csr);

    int MB64 = (NN + 63) / 64;  // 782

    // h = relu(x @ W_in + b_in) — x read exactly once (BN=256)
    mgemm_n256_kernel<1, 1, 1, 1><<<MB64, 256, 0, stream>>>(
        x, nullptr, WinT, b_in, h, hb, NN, INDIM);

    for (int l = 0; l < 2; l++) {
        mgemm_n256_kernel<0, 0, 0, 1><<<MB64, 256, 0, stream>>>(
            nullptr, hb, WgT[l], nullptr, nullptr, xhb, NN, HID);
        proj_al_kernel<<<(NN + 3) / 4, 256, 0, stream>>>(xhb, att_src[l], att_dst[l], al_s, al_d);
        agg_ln_kernel<<<(NN + 3) / 4, 256, 0, stream>>>(rowptr, csr, al_s, al_d, xhb,
                                                        b_gat[l], ln_g[l], ln_b[l], h, hb);
    }

    // classifier
    mgemm_kernel<0, 1, 1, 0><<<dim3((HID / 2) / 64, (NN + 127) / 128), 256, 0, stream>>>(
        nullptr, hb, Wc1T, b_c1, mid, nullptr, NN, HID, HID / 2);
    cls2_kernel<<<(NN * NCLS + 255) / 256, 256, 0, stream>>>(mid, W_c2, b_c2, (float*)d_out);
}